// Round 2
// baseline (7888.091 us; speedup 1.0000x reference)
//
#include <hip/hip_runtime.h>
#include <hip/hip_cooperative_groups.h>
#include <cmath>

namespace cg = cooperative_groups;

#define IN_DIM 1024
#define HD 256
#define G4H 1024
#define BB 64
#define TT 512
#define NCLS 8

/* h rings: 3 layers x 4 slots, 16384 floats per slot.
 * PAIR-INTERLEAVED slot layout: element (k,b) lives at (k>>1)*128 + b*2 + (k&1)
 * -> consumers load h as 8B (float2) agent atomics, fully coalesced. */
#define SLOT_STRIDE (HD * BB)          /* 16384 floats */
#define LAYER_STRIDE (4 * SLOT_STRIDE) /* 65536 floats */

__device__ __forceinline__ float sigmoidf_(float x) {
    return 1.0f / (1.0f + __expf(-x));
}
__device__ __forceinline__ float tanhf_(float x) {
    return 2.0f / (1.0f + __expf(-2.0f * x)) - 1.0f;
}
__device__ __forceinline__ float2 ld_agent2(const float* p) {
    unsigned long long r = __hip_atomic_load((const unsigned long long*)p,
                                             __ATOMIC_RELAXED, __HIP_MEMORY_SCOPE_AGENT);
    union { unsigned long long u; float2 f; } cv;
    cv.u = r;
    return cv.f;
}
__device__ __forceinline__ void st_agent(float* p, float v) {
    __hip_atomic_store(p, v, __ATOMIC_RELAXED, __HIP_MEMORY_SCOPE_AGENT);
}

/* ---------------- Kernel 1: xg0 = x @ Wih0^T + b0, stored (B*T, 4H) ---------------- */
#define GBM 128
#define GBN 128
#define GBK 16

__global__ __launch_bounds__(256) void xg0_gemm(const float* __restrict__ x,
                                                const float* __restrict__ Wih0,
                                                const float* __restrict__ b0,
                                                float* __restrict__ xg0) {
    __shared__ float As[GBK][GBM];
    __shared__ float Bs[GBK][GBN];
    const int m0 = blockIdx.y * GBM;
    const int n0 = blockIdx.x * GBN;
    const int tid = threadIdx.x;
    const int tx = tid & 15;
    const int ty = tid >> 4;
    const int lr = tid >> 1;
    const int lk = (tid & 1) * 8;
    float acc[8][8] = {};
    for (int k0 = 0; k0 < IN_DIM; k0 += GBK) {
        const float4 a0 = *(const float4*)&x[(size_t)(m0 + lr) * IN_DIM + k0 + lk];
        const float4 a1 = *(const float4*)&x[(size_t)(m0 + lr) * IN_DIM + k0 + lk + 4];
        const float4 w0 = *(const float4*)&Wih0[(size_t)(n0 + lr) * IN_DIM + k0 + lk];
        const float4 w1 = *(const float4*)&Wih0[(size_t)(n0 + lr) * IN_DIM + k0 + lk + 4];
        __syncthreads();
        As[lk + 0][lr] = a0.x; As[lk + 1][lr] = a0.y; As[lk + 2][lr] = a0.z; As[lk + 3][lr] = a0.w;
        As[lk + 4][lr] = a1.x; As[lk + 5][lr] = a1.y; As[lk + 6][lr] = a1.z; As[lk + 7][lr] = a1.w;
        Bs[lk + 0][lr] = w0.x; Bs[lk + 1][lr] = w0.y; Bs[lk + 2][lr] = w0.z; Bs[lk + 3][lr] = w0.w;
        Bs[lk + 4][lr] = w1.x; Bs[lk + 5][lr] = w1.y; Bs[lk + 6][lr] = w1.z; Bs[lk + 7][lr] = w1.w;
        __syncthreads();
#pragma unroll
        for (int k = 0; k < GBK; ++k) {
            const float4 av0 = *(const float4*)&As[k][ty * 8];
            const float4 av1 = *(const float4*)&As[k][ty * 8 + 4];
            const float4 bv0 = *(const float4*)&Bs[k][tx * 8];
            const float4 bv1 = *(const float4*)&Bs[k][tx * 8 + 4];
            const float am[8] = {av0.x, av0.y, av0.z, av0.w, av1.x, av1.y, av1.z, av1.w};
            const float bn[8] = {bv0.x, bv0.y, bv0.z, bv0.w, bv1.x, bv1.y, bv1.z, bv1.w};
#pragma unroll
            for (int i = 0; i < 8; ++i)
#pragma unroll
                for (int jj = 0; jj < 8; ++jj)
                    acc[i][jj] = fmaf(am[i], bn[jj], acc[i][jj]);
        }
    }
    const float4 bias0 = *(const float4*)&b0[n0 + tx * 8];
    const float4 bias1 = *(const float4*)&b0[n0 + tx * 8 + 4];
#pragma unroll
    for (int i = 0; i < 8; ++i) {
        const int m = m0 + ty * 8 + i;
        float4 v0, v1;
        v0.x = acc[i][0] + bias0.x; v0.y = acc[i][1] + bias0.y;
        v0.z = acc[i][2] + bias0.z; v0.w = acc[i][3] + bias0.w;
        v1.x = acc[i][4] + bias1.x; v1.y = acc[i][5] + bias1.y;
        v1.z = acc[i][6] + bias1.z; v1.w = acc[i][7] + bias1.w;
        *(float4*)&xg0[(size_t)m * G4H + n0 + tx * 8] = v0;
        *(float4*)&xg0[(size_t)m * G4H + n0 + tx * 8 + 4] = v1;
    }
}

/* ---------------- Kernel 2: 3-stage flag-synced LSTM ----------------
 * 192 blocks = 3 layers x 64 blocks. Block owns 4 cells (16 gate-rows) x all 64 b.
 * 512 threads = 8 waves; wave w owns k-chunk [32w, 32w+32).
 * Weights staged ONCE into LDS (32 KB/block); inner loop reads them as
 * wave-uniform ds_read_b128 (same-address broadcast, conflict-free, pipelined
 * with FMAs). h exchanged through agent-scope (LLC) 8B loads, batched into one
 * round trip; own-ring h load overlapped with the input-flag poll. */
__global__ __launch_bounds__(512) void lstm_cells(
    const float* __restrict__ xg0,
    const float* __restrict__ Whh0,
    const float* __restrict__ Wih1, const float* __restrict__ Whh1, const float* __restrict__ b1,
    const float* __restrict__ Wih2, const float* __restrict__ Whh2, const float* __restrict__ b2,
    float* __restrict__ hring, int* __restrict__ flags)
{
    cg::grid_group grid = cg::this_grid();
    const int blk = blockIdx.x;
    const int layer = blk >> 6;        // 0..2
    const int lb = blk & 63;
    const int jbase = lb * 4;
    const int tid = threadIdx.x;
    const int w = tid >> 6;            // wave index 0..7
    const int b = tid & 63;            // lane == batch
    const int kbase = w * 32;

    __shared__ float red[16 * 8 * 64];   // [row][wave][b] = 32 KB
    __shared__ float wlds[2][16][256];   // [hh/ih][row=jl*4+g][k] = 32 KB

    const float* Wih = (layer == 1) ? Wih1 : Wih2;
    const float* Whh = (layer == 0) ? Whh0 : ((layer == 1) ? Whh1 : Whh2);
    const float* bias = (layer == 1) ? b1 : b2;

    /* ---- stage this block's weight slice into LDS (once) ---- */
    for (int idx = tid; idx < 16 * 64; idx += 512) {
        const int r = idx >> 6;           // 0..15, r = jl*4 + g
        const int c = (idx & 63) << 2;    // float column
        const int jl = r >> 2, g = r & 3;
        *(float4*)&wlds[0][r][c] =
            *(const float4*)&Whh[(size_t)(g * HD + jbase + jl) * HD + c];
        if (layer > 0)
            *(float4*)&wlds[1][r][c] =
                *(const float4*)&Wih[(size_t)(g * HD + jbase + jl) * HD + c];
    }

    // zero rings + flags (ws is poisoned); plain stores, pushed out by grid.sync's release
    for (int i = blk * 512 + tid; i < 3 * LAYER_STRIDE; i += 192 * 512) hring[i] = 0.0f;
    for (int i = blk * 512 + tid; i < 3 * TT * 64; i += 192 * 512) flags[i] = 0;

    float bs0 = 0.f, bs1 = 0.f, bs2 = 0.f, bs3 = 0.f;
    if (layer > 0 && tid < 256) {
        bs0 = bias[0 * HD + jbase + w]; bs1 = bias[1 * HD + jbase + w];
        bs2 = bias[2 * HD + jbase + w]; bs3 = bias[3 * HD + jbase + w];
    }

    float* myring = hring + layer * LAYER_STRIDE;
    const float* inring = hring + (layer - 1) * LAYER_STRIDE;

    float c = 0.0f;

    grid.sync();   // rings/flags zeroed, wlds staged, all visible

    for (int t = 0; t < TT; ++t) {
        /* ---- layer-0 xg prefetch: issued BEFORE the poll, latency hides under it ---- */
        float xv0, xv1, xv2, xv3;
        if (layer == 0 && tid < 256) {
            const float* xg = xg0 + ((size_t)b * TT + t) * G4H + jbase + w;
            xv0 = xg[0 * HD]; xv1 = xg[1 * HD]; xv2 = xg[2 * HD]; xv3 = xg[3 * HD];
        }

        /* ---- poll 1: own h[t-1] ready + consumer drained our t-4 slot ---- */
        if (tid < 64) {
            const int* f_own = &flags[(layer * TT + (t - 1)) * 64 + tid];
            const int* f_nxt = &flags[((layer + 1) * TT + (t - 4)) * 64 + tid];
            const bool need_own = (t >= 1);
            const bool need_nxt = (layer < 2) && (t >= 4);
            for (;;) {
                int ok = 1;
                if (need_own) ok &= __hip_atomic_load(f_own, __ATOMIC_RELAXED, __HIP_MEMORY_SCOPE_AGENT);
                if (need_nxt) ok &= __hip_atomic_load(f_nxt, __ATOMIC_RELAXED, __HIP_MEMORY_SCOPE_AGENT);
                if (__all(ok)) break;
                __builtin_amdgcn_s_sleep(1);
            }
        }
        __syncthreads();
        __atomic_signal_fence(__ATOMIC_SEQ_CST);

        /* ---- own-ring h[t-1] loads: one LLC round trip, overlaps poll 2 ---- */
        float hv[32];
        {
            const float* hpv = myring + (size_t)((t + 3) & 3) * SLOT_STRIDE
                             + (size_t)(16 * w) * 128 + b * 2;
#pragma unroll
            for (int u2 = 0; u2 < 16; ++u2) {
                const float2 v = ld_agent2(hpv + u2 * 128);
                hv[2 * u2] = v.x; hv[2 * u2 + 1] = v.y;
            }
        }

        /* ---- poll 2 (layers 1,2): input h[t] ready; hv loads fly meanwhile ---- */
        float gv[32];
        if (layer > 0) {
            if (tid < 64) {
                const int* f_in = &flags[((layer - 1) * TT + t) * 64 + tid];
                for (;;) {
                    int ok = __hip_atomic_load(f_in, __ATOMIC_RELAXED, __HIP_MEMORY_SCOPE_AGENT);
                    if (__all(ok)) break;
                    __builtin_amdgcn_s_sleep(1);
                }
            }
            __syncthreads();
            __atomic_signal_fence(__ATOMIC_SEQ_CST);
            const float* hin = inring + (size_t)(t & 3) * SLOT_STRIDE
                             + (size_t)(16 * w) * 128 + b * 2;
#pragma unroll
            for (int u2 = 0; u2 < 16; ++u2) {
                const float2 v = ld_agent2(hin + u2 * 128);
                gv[2 * u2] = v.x; gv[2 * u2 + 1] = v.y;
            }
        }

        float acc[16];

        /* ---- hh partials: weights broadcast from LDS ---- */
#pragma unroll
        for (int r = 0; r < 16; ++r) {
            const float4* wr = (const float4*)&wlds[0][r][kbase];
            float a = 0.0f;
#pragma unroll
            for (int q = 0; q < 8; ++q) {
                const float4 wv = wr[q];
                a = fmaf(wv.x, hv[4 * q + 0], a);
                a = fmaf(wv.y, hv[4 * q + 1], a);
                a = fmaf(wv.z, hv[4 * q + 2], a);
                a = fmaf(wv.w, hv[4 * q + 3], a);
            }
            acc[r] = a;
        }
        /* ---- ih partials over h_{l-1}[t] (layers 1,2) ---- */
        if (layer > 0) {
#pragma unroll
            for (int r = 0; r < 16; ++r) {
                const float4* wr = (const float4*)&wlds[1][r][kbase];
                float a = acc[r];
#pragma unroll
                for (int q = 0; q < 8; ++q) {
                    const float4 wv = wr[q];
                    a = fmaf(wv.x, gv[4 * q + 0], a);
                    a = fmaf(wv.y, gv[4 * q + 1], a);
                    a = fmaf(wv.z, gv[4 * q + 2], a);
                    a = fmaf(wv.w, gv[4 * q + 3], a);
                }
                acc[r] = a;
            }
        }

        /* ---- cross-wave reduction via LDS: red[row][wave][b] ---- */
#pragma unroll
        for (int r = 0; r < 16; ++r) red[(r * 8 + w) * 64 + b] = acc[r];
        __syncthreads();

        /* ---- cell update: first 4 waves, thread = (cell j = w, b) ---- */
        if (tid < 256) {
            float a0, a1, a2, a3;
            if (layer == 0) { a0 = xv0; a1 = xv1; a2 = xv2; a3 = xv3; }
            else            { a0 = bs0; a1 = bs1; a2 = bs2; a3 = bs3; }
#pragma unroll
            for (int ww = 0; ww < 8; ++ww) {
                a0 += red[((w * 4 + 0) * 8 + ww) * 64 + b];
                a1 += red[((w * 4 + 1) * 8 + ww) * 64 + b];
                a2 += red[((w * 4 + 2) * 8 + ww) * 64 + b];
                a3 += red[((w * 4 + 3) * 8 + ww) * 64 + b];
            }
            const float ig = sigmoidf_(a0);
            const float fg = sigmoidf_(a1);
            const float gg = tanhf_(a2);
            const float og = sigmoidf_(a3);
            c = fg * c + ig * gg;
            const float h = og * tanhf_(c);
            /* j = jbase + w -> pair layout: (j>>1)*128 + b*2 + (j&1) */
            st_agent(&myring[(size_t)(t & 3) * SLOT_STRIDE
                             + (size_t)(lb * 2 + (w >> 1)) * 128 + b * 2 + (w & 1)], h);
        }

        __syncthreads();   // all waves' h stores drained (vmcnt(0)) before flag
        if (tid == 0) {
            __hip_atomic_store(&flags[(layer * TT + t) * 64 + lb], 1,
                               __ATOMIC_RELAXED, __HIP_MEMORY_SCOPE_AGENT);
        }
    }
}

/* ---------------- Kernel 3: FC head on h2[T-1] (pair layout) ---------------- */
__global__ __launch_bounds__(256) void classifier_k(
    const float* __restrict__ hring,
    const float* __restrict__ W1, const float* __restrict__ bfc1,
    const float* __restrict__ W2, const float* __restrict__ bfc2,
    float* __restrict__ out)
{
    __shared__ float z[BB * 128];
    const float* h2T = hring + 2 * LAYER_STRIDE + (size_t)((TT - 1) & 3) * SLOT_STRIDE;
    const int tid = threadIdx.x;
    for (int idx = tid; idx < BB * 128; idx += 256) {
        const int bb = idx >> 7;
        const int n = idx & 127;
        float acc = bfc1[n];
        const float* wr = W1 + (size_t)n * HD;
        for (int k2 = 0; k2 < HD / 2; ++k2) {
            const float2 hvv = *(const float2*)&h2T[k2 * 128 + bb * 2];
            acc = fmaf(hvv.x, wr[2 * k2], acc);
            acc = fmaf(hvv.y, wr[2 * k2 + 1], acc);
        }
        z[bb * 128 + n] = fmaxf(acc, 0.0f);
    }
    __syncthreads();
    for (int idx = tid; idx < BB * NCLS; idx += 256) {
        const int bb = idx >> 3;
        const int n = idx & 7;
        float acc = bfc2[n];
        const float* zr = &z[bb * 128];
        const float* wr = W2 + (size_t)n * 128;
        for (int k = 0; k < 128; k += 4) {
            const float4 zv = *(const float4*)&zr[k];
            const float4 wv = *(const float4*)&wr[k];
            acc = fmaf(zv.x, wv.x, acc); acc = fmaf(zv.y, wv.y, acc);
            acc = fmaf(zv.z, wv.z, acc); acc = fmaf(zv.w, wv.w, acc);
        }
        out[idx] = acc;
    }
}

extern "C" void kernel_launch(void* const* d_in, const int* in_sizes, int n_in,
                              void* d_out, int out_size, void* d_ws, size_t ws_size,
                              hipStream_t stream) {
    const float* x    = (const float*)d_in[0];
    const float* Wih0 = (const float*)d_in[1];
    const float* Whh0 = (const float*)d_in[2];
    const float* b0   = (const float*)d_in[3];
    const float* Wih1 = (const float*)d_in[4];
    const float* Whh1 = (const float*)d_in[5];
    const float* b1   = (const float*)d_in[6];
    const float* Wih2 = (const float*)d_in[7];
    const float* Whh2 = (const float*)d_in[8];
    const float* b2   = (const float*)d_in[9];
    const float* W1   = (const float*)d_in[10];
    const float* bfc1 = (const float*)d_in[11];
    const float* W2   = (const float*)d_in[12];
    const float* bfc2 = (const float*)d_in[13];

    float* xg0   = (float*)d_ws;                       // B*T*4H fp32 = 134.2 MB
    float* hring = xg0 + (size_t)BB * TT * G4H;        // 786 KB
    int*   flags = (int*)(hring + 3 * LAYER_STRIDE);   // 3*512*64 ints = 393 KB

    xg0_gemm<<<dim3(G4H / GBN, (BB * TT) / GBM), 256, 0, stream>>>(x, Wih0, b0, xg0);

    const float* xg0c = xg0;
    float* hr = hring;
    int* fl = flags;
    void* args[] = {
        (void*)&xg0c, (void*)&Whh0,
        (void*)&Wih1, (void*)&Whh1, (void*)&b1,
        (void*)&Wih2, (void*)&Whh2, (void*)&b2,
        (void*)&hr, (void*)&fl
    };
    hipLaunchCooperativeKernel((void*)lstm_cells, dim3(192), dim3(512), args, 0, stream);

    classifier_k<<<1, 256, 0, stream>>>(hring, W1, bfc1, W2, bfc2, (float*)d_out);
}

// Round 4
// 6909.008 us; speedup vs baseline: 1.1417x; 1.1417x over previous
//
#include <hip/hip_runtime.h>
#include <hip/hip_cooperative_groups.h>
#include <cmath>

namespace cg = cooperative_groups;

#define IN_DIM 1024
#define HD 256
#define G4H 1024
#define BB 64
#define TT 512
#define NCLS 8

/* h rings: 3 layers x 4 slots, 16384 ELEMENTS per slot.
 * Each element is 8 bytes: {tag:hi32, h_bits:lo32}, written/read with ONE
 * relaxed agent-scope 8B atomic -> the tag travels WITH the data (flag fused
 * into payload; single LLC round trip). Element (k,b) at [k*64 + b]. */
#define SLOT_STRIDE (HD * BB)          /* 16384 elements */
#define LAYER_STRIDE (4 * SLOT_STRIDE) /* 65536 elements */

__device__ __forceinline__ float sigmoidf_(float x) {
    return 1.0f / (1.0f + __expf(-x));
}
__device__ __forceinline__ float tanhf_(float x) {
    return 2.0f / (1.0f + __expf(-2.0f * x)) - 1.0f;
}
__device__ __forceinline__ unsigned long long ld_agent_u64(const unsigned long long* p) {
    return __hip_atomic_load(p, __ATOMIC_RELAXED, __HIP_MEMORY_SCOPE_AGENT);
}
__device__ __forceinline__ void st_agent_u64(unsigned long long* p, unsigned long long v) {
    __hip_atomic_store(p, v, __ATOMIC_RELAXED, __HIP_MEMORY_SCOPE_AGENT);
}

/* ---------------- Kernel 1: xg0T[t][n][b] = (x @ Wih0^T + b0) transposed ----------------
 * Logical GEMM row m = t*64 + b; A row = x[b][t] (row permutation: per-lane
 * float4 loads unchanged). Output stored TRANSPOSED (T, 4H, B) so the LSTM's
 * layer-0 gate loads are coalesced 64-lane reads. Epilogue stores are
 * scattered scalar but off the critical path; L2 merges them. */
#define GBM 128
#define GBN 128
#define GBK 16

__global__ __launch_bounds__(256) void xg0_gemm(const float* __restrict__ x,
                                                const float* __restrict__ Wih0,
                                                const float* __restrict__ b0,
                                                float* __restrict__ xg0T) {
    __shared__ float As[GBK][GBM];
    __shared__ float Bs[GBK][GBN];
    const int m0 = blockIdx.y * GBM;
    const int n0 = blockIdx.x * GBN;
    const int tid = threadIdx.x;
    const int tx = tid & 15;
    const int ty = tid >> 4;
    const int lr = tid >> 1;
    const int lk = (tid & 1) * 8;
    /* permuted A row for logical row m0+lr: b = (m&63), t = (m>>6) */
    const int am = m0 + lr;
    const size_t arow = (size_t)(am & 63) * TT + (am >> 6);
    float acc[8][8] = {};
    for (int k0 = 0; k0 < IN_DIM; k0 += GBK) {
        const float4 a0 = *(const float4*)&x[arow * IN_DIM + k0 + lk];
        const float4 a1 = *(const float4*)&x[arow * IN_DIM + k0 + lk + 4];
        const float4 w0 = *(const float4*)&Wih0[(size_t)(n0 + lr) * IN_DIM + k0 + lk];
        const float4 w1 = *(const float4*)&Wih0[(size_t)(n0 + lr) * IN_DIM + k0 + lk + 4];
        __syncthreads();
        As[lk + 0][lr] = a0.x; As[lk + 1][lr] = a0.y; As[lk + 2][lr] = a0.z; As[lk + 3][lr] = a0.w;
        As[lk + 4][lr] = a1.x; As[lk + 5][lr] = a1.y; As[lk + 6][lr] = a1.z; As[lk + 7][lr] = a1.w;
        Bs[lk + 0][lr] = w0.x; Bs[lk + 1][lr] = w0.y; Bs[lk + 2][lr] = w0.z; Bs[lk + 3][lr] = w0.w;
        Bs[lk + 4][lr] = w1.x; Bs[lk + 5][lr] = w1.y; Bs[lk + 6][lr] = w1.z; Bs[lk + 7][lr] = w1.w;
        __syncthreads();
#pragma unroll
        for (int k = 0; k < GBK; ++k) {
            const float4 av0 = *(const float4*)&As[k][ty * 8];
            const float4 av1 = *(const float4*)&As[k][ty * 8 + 4];
            const float4 bv0 = *(const float4*)&Bs[k][tx * 8];
            const float4 bv1 = *(const float4*)&Bs[k][tx * 8 + 4];
            const float am8[8] = {av0.x, av0.y, av0.z, av0.w, av1.x, av1.y, av1.z, av1.w};
            const float bn8[8] = {bv0.x, bv0.y, bv0.z, bv0.w, bv1.x, bv1.y, bv1.z, bv1.w};
#pragma unroll
            for (int i = 0; i < 8; ++i)
#pragma unroll
                for (int jj = 0; jj < 8; ++jj)
                    acc[i][jj] = fmaf(am8[i], bn8[jj], acc[i][jj]);
        }
    }
    const float4 bias0 = *(const float4*)&b0[n0 + tx * 8];
    const float4 bias1 = *(const float4*)&b0[n0 + tx * 8 + 4];
    const float bia[8] = {bias0.x, bias0.y, bias0.z, bias0.w, bias1.x, bias1.y, bias1.z, bias1.w};
#pragma unroll
    for (int i = 0; i < 8; ++i) {
        const int m = m0 + ty * 8 + i;
        const int t = m >> 6;
        const int bb = m & 63;
#pragma unroll
        for (int jj = 0; jj < 8; ++jj) {
            const int n = n0 + tx * 8 + jj;
            xg0T[((size_t)t * G4H + n) * BB + bb] = acc[i][jj] + bia[jj];
        }
    }
}

/* ---------------- Kernel 2: 3-stage tag-synced LSTM ----------------
 * 192 blocks = 3 layers x 64 blocks. Block owns 4 cells x all 64 b.
 * 512 threads = 8 waves; wave w owns k-chunk [32w, 32w+32).
 * h exchange: tagged 8B elements (tag=t+1 fused with data) -> consumer polls
 * the data itself, ONE LLC round trip, per-wave independent progress.
 * Weights staged once in LDS, read as wave-uniform broadcasts.
 * LDS held at 64 KB (proven-launch envelope): red single-buffered, two
 * barriers per step. Completion flags only as slot-drain back-pressure. */
__global__ __launch_bounds__(512) void lstm_cells(
    const float* __restrict__ xg0T,
    const float* __restrict__ Whh0,
    const float* __restrict__ Wih1, const float* __restrict__ Whh1, const float* __restrict__ b1,
    const float* __restrict__ Wih2, const float* __restrict__ Whh2, const float* __restrict__ b2,
    unsigned long long* __restrict__ ringU, int* __restrict__ flags)
{
    cg::grid_group grid = cg::this_grid();
    const int blk = blockIdx.x;
    const int layer = blk >> 6;        // 0..2
    const int lb = blk & 63;
    const int jbase = lb * 4;
    const int tid = threadIdx.x;
    const int w = tid >> 6;            // wave index 0..7
    const int b = tid & 63;            // lane == batch
    const int kbase = w * 32;

    __shared__ float red[16][8][64];     // [row][wave][b] = 32 KB
    __shared__ float wlds[2][16][256];   // [hh/ih][row=jl*4+g][k] = 32 KB  -> 64 KB total

    const float* Wih = (layer == 1) ? Wih1 : Wih2;
    const float* Whh = (layer == 0) ? Whh0 : ((layer == 1) ? Whh1 : Whh2);
    const float* bias = (layer == 1) ? b1 : b2;

    /* ---- stage this block's weight slice into LDS (once) ---- */
    for (int idx = tid; idx < 16 * 64; idx += 512) {
        const int r = idx >> 6;           // 0..15, r = jl*4 + g
        const int cc = (idx & 63) << 2;   // float column
        const int jl = r >> 2, g = r & 3;
        *(float4*)&wlds[0][r][cc] =
            *(const float4*)&Whh[(size_t)(g * HD + jbase + jl) * HD + cc];
        if (layer > 0)
            *(float4*)&wlds[1][r][cc] =
                *(const float4*)&Wih[(size_t)(g * HD + jbase + jl) * HD + cc];
    }

    /* zero ring (tag=0, h=0) + flags; visible after grid.sync */
    for (int i = blk * 512 + tid; i < 3 * LAYER_STRIDE; i += 192 * 512) ringU[i] = 0ull;
    for (int i = blk * 512 + tid; i < 3 * TT * 64; i += 192 * 512) flags[i] = 0;

    float bs0 = 0.f, bs1 = 0.f, bs2 = 0.f, bs3 = 0.f;
    if (layer > 0 && tid < 256) {
        bs0 = bias[0 * HD + jbase + w]; bs1 = bias[1 * HD + jbase + w];
        bs2 = bias[2 * HD + jbase + w]; bs3 = bias[3 * HD + jbase + w];
    }

    unsigned long long* myU = ringU + (size_t)layer * LAYER_STRIDE;
    const unsigned long long* inU = ringU + (size_t)(layer - 1) * LAYER_STRIDE;

    float c = 0.0f;

    grid.sync();   // ring/flags zeroed, wlds staged, all visible

    for (int t = 0; t < TT; ++t) {
        /* ---- layer-0 xg prefetch: coalesced from xg0T, issued first ---- */
        float xv0, xv1, xv2, xv3;
        if (layer == 0 && tid < 256) {
            const float* xg = xg0T + ((size_t)t * G4H + jbase + w) * BB + b;
            xv0 = xg[0 * HD * BB]; xv1 = xg[1 * HD * BB];
            xv2 = xg[2 * HD * BB]; xv3 = xg[3 * HD * BB];
        }
        __atomic_signal_fence(__ATOMIC_SEQ_CST);   // pin xg issue before polls

        /* ---- back-pressure: consumer must have consumed our slot (t-4) ---- */
        if (layer < 2 && t >= 4 && tid < 64) {
            const int* f_nxt = &flags[((layer + 1) * TT + (t - 4)) * 64 + tid];
            for (;;) {
                int ok = __hip_atomic_load(f_nxt, __ATOMIC_RELAXED, __HIP_MEMORY_SCOPE_AGENT);
                if (__all(ok)) break;
                __builtin_amdgcn_s_sleep(2);
            }
        }

        /* ---- own h[t-1]: tagged loads, poll data directly (1 RT) ---- */
        float hv[32];
        {
            const unsigned long long* hp = myU + (size_t)((t + 3) & 3) * SLOT_STRIDE
                                         + (size_t)kbase * BB + b;
            const unsigned want = (unsigned)t;   // tag written at t-1 is (t-1)+1
            unsigned long long v[32];
            for (;;) {
#pragma unroll
                for (int u = 0; u < 32; ++u) v[u] = ld_agent_u64(hp + (size_t)u * BB);
                unsigned ok = 1;
#pragma unroll
                for (int u = 0; u < 32; ++u) ok &= ((unsigned)(v[u] >> 32) == want) ? 1u : 0u;
                if (__all(ok != 0)) break;
                __builtin_amdgcn_s_sleep(2);
            }
#pragma unroll
            for (int u = 0; u < 32; ++u) hv[u] = __uint_as_float((unsigned)v[u]);
        }

        /* ---- input h[t] from layer-1 (layers 1,2): tagged loads (1 RT) ---- */
        float gv[32];
        if (layer > 0) {
            const unsigned long long* gp = inU + (size_t)(t & 3) * SLOT_STRIDE
                                         + (size_t)kbase * BB + b;
            const unsigned want = (unsigned)(t + 1);
            unsigned long long v[32];
            for (;;) {
#pragma unroll
                for (int u = 0; u < 32; ++u) v[u] = ld_agent_u64(gp + (size_t)u * BB);
                unsigned ok = 1;
#pragma unroll
                for (int u = 0; u < 32; ++u) ok &= ((unsigned)(v[u] >> 32) == want) ? 1u : 0u;
                if (__all(ok != 0)) break;
                __builtin_amdgcn_s_sleep(2);
            }
#pragma unroll
            for (int u = 0; u < 32; ++u) gv[u] = __uint_as_float((unsigned)v[u]);
        }

        /* ---- partials: weights broadcast from LDS ---- */
        float acc[16];
#pragma unroll
        for (int r = 0; r < 16; ++r) {
            const float4* wr0 = (const float4*)&wlds[0][r][kbase];
            float a = 0.0f;
#pragma unroll
            for (int q = 0; q < 8; ++q) {
                const float4 wv = wr0[q];
                a = fmaf(wv.x, hv[4 * q + 0], a);
                a = fmaf(wv.y, hv[4 * q + 1], a);
                a = fmaf(wv.z, hv[4 * q + 2], a);
                a = fmaf(wv.w, hv[4 * q + 3], a);
            }
            if (layer > 0) {
                const float4* wr1 = (const float4*)&wlds[1][r][kbase];
#pragma unroll
                for (int q = 0; q < 8; ++q) {
                    const float4 wv = wr1[q];
                    a = fmaf(wv.x, gv[4 * q + 0], a);
                    a = fmaf(wv.y, gv[4 * q + 1], a);
                    a = fmaf(wv.z, gv[4 * q + 2], a);
                    a = fmaf(wv.w, gv[4 * q + 3], a);
                }
            }
            acc[r] = a;
        }

        /* ---- cross-wave reduction ---- */
#pragma unroll
        for (int r = 0; r < 16; ++r) red[r][w][b] = acc[r];
        __syncthreads();

        /* completion flag (slot-drain for producer): inputs of step t consumed */
        if (tid == 0) {
            __hip_atomic_store(&flags[(layer * TT + t) * 64 + lb], 1,
                               __ATOMIC_RELAXED, __HIP_MEMORY_SCOPE_AGENT);
        }

        /* ---- cell update: waves 0-3, thread = (cell j = w, b) ---- */
        if (tid < 256) {
            float a0, a1, a2, a3;
            if (layer == 0) { a0 = xv0; a1 = xv1; a2 = xv2; a3 = xv3; }
            else            { a0 = bs0; a1 = bs1; a2 = bs2; a3 = bs3; }
#pragma unroll
            for (int ww = 0; ww < 8; ++ww) {
                a0 += red[w * 4 + 0][ww][b];
                a1 += red[w * 4 + 1][ww][b];
                a2 += red[w * 4 + 2][ww][b];
                a3 += red[w * 4 + 3][ww][b];
            }
            const float ig = sigmoidf_(a0);
            const float fg = sigmoidf_(a1);
            const float gg = tanhf_(a2);
            const float og = sigmoidf_(a3);
            c = fg * c + ig * gg;
            const float h = og * tanhf_(c);
            const unsigned long long pk =
                ((unsigned long long)(unsigned)(t + 1) << 32) |
                (unsigned long long)__float_as_uint(h);
            st_agent_u64(&myU[(size_t)(t & 3) * SLOT_STRIDE
                              + (size_t)(jbase + w) * BB + b], pk);
        }

        __syncthreads();   // red reads done before next step's writes
    }
}

/* ---------------- Kernel 3: FC head on h2[T-1] (tagged-element layout) ---------------- */
__global__ __launch_bounds__(256) void classifier_k(
    const unsigned long long* __restrict__ ringU,
    const float* __restrict__ W1, const float* __restrict__ bfc1,
    const float* __restrict__ W2, const float* __restrict__ bfc2,
    float* __restrict__ out)
{
    __shared__ float z[BB * 128];
    const unsigned long long* h2T = ringU + 2 * LAYER_STRIDE
                                  + (size_t)((TT - 1) & 3) * SLOT_STRIDE;
    const int tid = threadIdx.x;
    for (int idx = tid; idx < BB * 128; idx += 256) {
        const int bb = idx >> 7;
        const int n = idx & 127;
        float acc = bfc1[n];
        const float* wr = W1 + (size_t)n * HD;
        for (int k = 0; k < HD; ++k) {
            const float hval = __uint_as_float((unsigned)h2T[(size_t)k * BB + bb]);
            acc = fmaf(hval, wr[k], acc);
        }
        z[bb * 128 + n] = fmaxf(acc, 0.0f);
    }
    __syncthreads();
    for (int idx = tid; idx < BB * NCLS; idx += 256) {
        const int bb = idx >> 3;
        const int n = idx & 7;
        float acc = bfc2[n];
        const float* zr = &z[bb * 128];
        const float* wr = W2 + (size_t)n * 128;
        for (int k = 0; k < 128; k += 4) {
            const float4 zv = *(const float4*)&zr[k];
            const float4 wv = *(const float4*)&wr[k];
            acc = fmaf(zv.x, wv.x, acc); acc = fmaf(zv.y, wv.y, acc);
            acc = fmaf(zv.z, wv.z, acc); acc = fmaf(zv.w, wv.w, acc);
        }
        out[idx] = acc;
    }
}

extern "C" void kernel_launch(void* const* d_in, const int* in_sizes, int n_in,
                              void* d_out, int out_size, void* d_ws, size_t ws_size,
                              hipStream_t stream) {
    const float* x    = (const float*)d_in[0];
    const float* Wih0 = (const float*)d_in[1];
    const float* Whh0 = (const float*)d_in[2];
    const float* b0   = (const float*)d_in[3];
    const float* Wih1 = (const float*)d_in[4];
    const float* Whh1 = (const float*)d_in[5];
    const float* b1   = (const float*)d_in[6];
    const float* Wih2 = (const float*)d_in[7];
    const float* Whh2 = (const float*)d_in[8];
    const float* b2   = (const float*)d_in[9];
    const float* W1   = (const float*)d_in[10];
    const float* bfc1 = (const float*)d_in[11];
    const float* W2   = (const float*)d_in[12];
    const float* bfc2 = (const float*)d_in[13];

    float* xg0T = (float*)d_ws;                               // B*T*4H fp32 = 134.2 MB
    unsigned long long* ringU =
        (unsigned long long*)(xg0T + (size_t)BB * TT * G4H);  // 3*4*16384 * 8B = 1.57 MB
    int* flags = (int*)(ringU + 3 * LAYER_STRIDE);            // 3*512*64 ints = 393 KB

    xg0_gemm<<<dim3(G4H / GBN, (BB * TT) / GBM), 256, 0, stream>>>(x, Wih0, b0, xg0T);

    const float* xgc = xg0T;
    unsigned long long* ru = ringU;
    int* fl = flags;
    void* args[] = {
        (void*)&xgc, (void*)&Whh0,
        (void*)&Wih1, (void*)&Whh1, (void*)&b1,
        (void*)&Wih2, (void*)&Whh2, (void*)&b2,
        (void*)&ru, (void*)&fl
    };
    hipLaunchCooperativeKernel((void*)lstm_cells, dim3(192), dim3(512), args, 0, stream);

    classifier_k<<<1, 256, 0, stream>>>(ringU, W1, bfc1, W2, bfc2, (float*)d_out);
}

// Round 5
// 6839.293 us; speedup vs baseline: 1.1533x; 1.0102x over previous
//
#include <hip/hip_runtime.h>
#include <hip/hip_cooperative_groups.h>
#include <cmath>

namespace cg = cooperative_groups;

#define IN_DIM 1024
#define HD 256
#define G4H 1024
#define BB 64
#define TT 512
#define NCLS 8

/* h rings: 3 layers x 4 slots, 16384 ELEMENTS per slot.
 * Each element is 8 bytes: {tag:hi32, h_bits:lo32}, written/read with ONE
 * relaxed agent-scope 8B atomic -> the tag travels WITH the data (flag fused
 * into payload; single LLC round trip). Element (k,b) at [k*64 + b]. */
#define SLOT_STRIDE (HD * BB)          /* 16384 elements */
#define LAYER_STRIDE (4 * SLOT_STRIDE) /* 65536 elements */

__device__ __forceinline__ float sigmoidf_(float x) {
    return 1.0f / (1.0f + __expf(-x));
}
__device__ __forceinline__ float tanhf_(float x) {
    return 2.0f / (1.0f + __expf(-2.0f * x)) - 1.0f;
}
__device__ __forceinline__ unsigned long long ld_agent_u64(const unsigned long long* p) {
    return __hip_atomic_load(p, __ATOMIC_RELAXED, __HIP_MEMORY_SCOPE_AGENT);
}
__device__ __forceinline__ void st_agent_u64(unsigned long long* p, unsigned long long v) {
    __hip_atomic_store(p, v, __ATOMIC_RELAXED, __HIP_MEMORY_SCOPE_AGENT);
}

/* ---------------- Kernel 1: xg0T[t][n][b] = (x @ Wih0^T + b0) transposed ---------------- */
#define GBM 128
#define GBN 128
#define GBK 16

__global__ __launch_bounds__(256) void xg0_gemm(const float* __restrict__ x,
                                                const float* __restrict__ Wih0,
                                                const float* __restrict__ b0,
                                                float* __restrict__ xg0T) {
    __shared__ float As[GBK][GBM];
    __shared__ float Bs[GBK][GBN];
    const int m0 = blockIdx.y * GBM;
    const int n0 = blockIdx.x * GBN;
    const int tid = threadIdx.x;
    const int tx = tid & 15;
    const int ty = tid >> 4;
    const int lr = tid >> 1;
    const int lk = (tid & 1) * 8;
    /* permuted A row for logical row m0+lr: b = (m&63), t = (m>>6) */
    const int am = m0 + lr;
    const size_t arow = (size_t)(am & 63) * TT + (am >> 6);
    float acc[8][8] = {};
    for (int k0 = 0; k0 < IN_DIM; k0 += GBK) {
        const float4 a0 = *(const float4*)&x[arow * IN_DIM + k0 + lk];
        const float4 a1 = *(const float4*)&x[arow * IN_DIM + k0 + lk + 4];
        const float4 w0 = *(const float4*)&Wih0[(size_t)(n0 + lr) * IN_DIM + k0 + lk];
        const float4 w1 = *(const float4*)&Wih0[(size_t)(n0 + lr) * IN_DIM + k0 + lk + 4];
        __syncthreads();
        As[lk + 0][lr] = a0.x; As[lk + 1][lr] = a0.y; As[lk + 2][lr] = a0.z; As[lk + 3][lr] = a0.w;
        As[lk + 4][lr] = a1.x; As[lk + 5][lr] = a1.y; As[lk + 6][lr] = a1.z; As[lk + 7][lr] = a1.w;
        Bs[lk + 0][lr] = w0.x; Bs[lk + 1][lr] = w0.y; Bs[lk + 2][lr] = w0.z; Bs[lk + 3][lr] = w0.w;
        Bs[lk + 4][lr] = w1.x; Bs[lk + 5][lr] = w1.y; Bs[lk + 6][lr] = w1.z; Bs[lk + 7][lr] = w1.w;
        __syncthreads();
#pragma unroll
        for (int k = 0; k < GBK; ++k) {
            const float4 av0 = *(const float4*)&As[k][ty * 8];
            const float4 av1 = *(const float4*)&As[k][ty * 8 + 4];
            const float4 bv0 = *(const float4*)&Bs[k][tx * 8];
            const float4 bv1 = *(const float4*)&Bs[k][tx * 8 + 4];
            const float am8[8] = {av0.x, av0.y, av0.z, av0.w, av1.x, av1.y, av1.z, av1.w};
            const float bn8[8] = {bv0.x, bv0.y, bv0.z, bv0.w, bv1.x, bv1.y, bv1.z, bv1.w};
#pragma unroll
            for (int i = 0; i < 8; ++i)
#pragma unroll
                for (int jj = 0; jj < 8; ++jj)
                    acc[i][jj] = fmaf(am8[i], bn8[jj], acc[i][jj]);
        }
    }
    const float4 bias0 = *(const float4*)&b0[n0 + tx * 8];
    const float4 bias1 = *(const float4*)&b0[n0 + tx * 8 + 4];
    const float bia[8] = {bias0.x, bias0.y, bias0.z, bias0.w, bias1.x, bias1.y, bias1.z, bias1.w};
#pragma unroll
    for (int i = 0; i < 8; ++i) {
        const int m = m0 + ty * 8 + i;
        const int t = m >> 6;
        const int bb = m & 63;
#pragma unroll
        for (int jj = 0; jj < 8; ++jj) {
            const int n = n0 + tx * 8 + jj;
            xg0T[((size_t)t * G4H + n) * BB + bb] = acc[i][jj] + bia[jj];
        }
    }
}

/* ---------------- Kernel 2: 3-stage tag-synced LSTM, VGPR-resident weights ----------------
 * 192 blocks = 3 layers x 64 blocks. Block owns 4 cells x all 64 b.
 * 512 threads = 8 waves; wave w owns k-chunk [32w, 32w+32).
 * WEIGHTS LIVE IN REGISTERS: wave's tile is 16 rows x 32 k = 2 KB = 8 floats
 * per lane per matrix, staged once before the t-loop. Inner loop broadcasts
 * each weight via v_readlane (compile-time lane index -> SGPR) feeding v_fma
 * directly: ZERO memory-pipe traffic per MAC (the R1/R2/R4 plateau was the
 * per-instr cost of SMEM/LDS weight delivery, ~2048 LDS instrs/CU/step).
 * h exchange: tagged 8B elements (tag=t+1 fused with data), agent scope.
 * LDS holds only the cross-wave reduction buffer (32 KB). */
__global__ __launch_bounds__(512) void lstm_cells(
    const float* __restrict__ xg0T,
    const float* __restrict__ Whh0,
    const float* __restrict__ Wih1, const float* __restrict__ Whh1, const float* __restrict__ b1,
    const float* __restrict__ Wih2, const float* __restrict__ Whh2, const float* __restrict__ b2,
    unsigned long long* __restrict__ ringU, int* __restrict__ flags)
{
    cg::grid_group grid = cg::this_grid();
    const int blk = blockIdx.x;
    const int layer = blk >> 6;        // 0..2
    const int lb = blk & 63;
    const int jbase = lb * 4;
    const int tid = threadIdx.x;
    const int w = tid >> 6;            // wave index 0..7
    const int b = tid & 63;            // lane == batch (compute phase)
    const int kbase = w * 32;

    __shared__ float red[16][8][64];   // [row][wave][b] = 32 KB (only LDS)

    const float* Wih = (layer == 1) ? Wih1 : Wih2;
    const float* Whh = (layer == 0) ? Whh0 : ((layer == 1) ? Whh1 : Whh2);
    const float* bias = (layer == 1) ? b1 : b2;

    /* ---- stage wave's weight tile into per-lane VGPRs (once) ----
     * lane l holds rows r = l>>2 (of 16), k-sub (l&3)*8 .. +7 of the wave's
     * 32-k chunk. Element (r, q*8+u) is read back via readlane(reg u, r*4+q). */
    float whreg[8];
    float wihreg[8];
    {
        const int r = b >> 2;          // 0..15 = jl*4+g mapping below
        const int jl = r >> 2;
        const int g = r & 3;
        const int kofs = kbase + (b & 3) * 8;
        const float4 h0 = *(const float4*)&Whh[(size_t)(g * HD + jbase + jl) * HD + kofs];
        const float4 h1 = *(const float4*)&Whh[(size_t)(g * HD + jbase + jl) * HD + kofs + 4];
        whreg[0] = h0.x; whreg[1] = h0.y; whreg[2] = h0.z; whreg[3] = h0.w;
        whreg[4] = h1.x; whreg[5] = h1.y; whreg[6] = h1.z; whreg[7] = h1.w;
        if (layer > 0) {
            const float4 i0 = *(const float4*)&Wih[(size_t)(g * HD + jbase + jl) * HD + kofs];
            const float4 i1 = *(const float4*)&Wih[(size_t)(g * HD + jbase + jl) * HD + kofs + 4];
            wihreg[0] = i0.x; wihreg[1] = i0.y; wihreg[2] = i0.z; wihreg[3] = i0.w;
            wihreg[4] = i1.x; wihreg[5] = i1.y; wihreg[6] = i1.z; wihreg[7] = i1.w;
        } else {
#pragma unroll
            for (int u = 0; u < 8; ++u) wihreg[u] = 0.0f;
        }
    }

    /* zero ring (tag=0, h=0) + flags; visible after grid.sync */
    for (int i = blk * 512 + tid; i < 3 * LAYER_STRIDE; i += 192 * 512) ringU[i] = 0ull;
    for (int i = blk * 512 + tid; i < 3 * TT * 64; i += 192 * 512) flags[i] = 0;

    float bs0 = 0.f, bs1 = 0.f, bs2 = 0.f, bs3 = 0.f;
    if (layer > 0 && tid < 256) {
        bs0 = bias[0 * HD + jbase + w]; bs1 = bias[1 * HD + jbase + w];
        bs2 = bias[2 * HD + jbase + w]; bs3 = bias[3 * HD + jbase + w];
    }

    unsigned long long* myU = ringU + (size_t)layer * LAYER_STRIDE;
    const unsigned long long* inU = ringU + (size_t)(layer - 1) * LAYER_STRIDE;

    float c = 0.0f;

    grid.sync();   // ring/flags zeroed, weights staged, all visible

    for (int t = 0; t < TT; ++t) {
        /* ---- layer-0 xg prefetch: coalesced from xg0T, issued first ---- */
        float xv0, xv1, xv2, xv3;
        if (layer == 0 && tid < 256) {
            const float* xg = xg0T + ((size_t)t * G4H + jbase + w) * BB + b;
            xv0 = xg[0 * HD * BB]; xv1 = xg[1 * HD * BB];
            xv2 = xg[2 * HD * BB]; xv3 = xg[3 * HD * BB];
        }
        __atomic_signal_fence(__ATOMIC_SEQ_CST);   // pin xg issue before polls

        /* ---- back-pressure: consumer must have consumed our slot (t-4) ---- */
        if (layer < 2 && t >= 4 && tid < 64) {
            const int* f_nxt = &flags[((layer + 1) * TT + (t - 4)) * 64 + tid];
            for (;;) {
                int ok = __hip_atomic_load(f_nxt, __ATOMIC_RELAXED, __HIP_MEMORY_SCOPE_AGENT);
                if (__all(ok)) break;
                __builtin_amdgcn_s_sleep(2);
            }
        }

        /* ---- own h[t-1]: tagged loads, poll data directly (1 RT) ---- */
        float hv[32];
        {
            const unsigned long long* hp = myU + (size_t)((t + 3) & 3) * SLOT_STRIDE
                                         + (size_t)kbase * BB + b;
            const unsigned want = (unsigned)t;   // tag written at t-1 is (t-1)+1
            unsigned long long v[32];
            for (;;) {
#pragma unroll
                for (int u = 0; u < 32; ++u) v[u] = ld_agent_u64(hp + (size_t)u * BB);
                unsigned ok = 1;
#pragma unroll
                for (int u = 0; u < 32; ++u) ok &= ((unsigned)(v[u] >> 32) == want) ? 1u : 0u;
                if (__all(ok != 0)) break;
                __builtin_amdgcn_s_sleep(2);
            }
#pragma unroll
            for (int u = 0; u < 32; ++u) hv[u] = __uint_as_float((unsigned)v[u]);
        }

        /* ---- input h[t] from layer-1 (layers 1,2): tagged loads (1 RT) ---- */
        float gv[32];
        if (layer > 0) {
            const unsigned long long* gp = inU + (size_t)(t & 3) * SLOT_STRIDE
                                         + (size_t)kbase * BB + b;
            const unsigned want = (unsigned)(t + 1);
            unsigned long long v[32];
            for (;;) {
#pragma unroll
                for (int u = 0; u < 32; ++u) v[u] = ld_agent_u64(gp + (size_t)u * BB);
                unsigned ok = 1;
#pragma unroll
                for (int u = 0; u < 32; ++u) ok &= ((unsigned)(v[u] >> 32) == want) ? 1u : 0u;
                if (__all(ok != 0)) break;
                __builtin_amdgcn_s_sleep(2);
            }
#pragma unroll
            for (int u = 0; u < 32; ++u) gv[u] = __uint_as_float((unsigned)v[u]);
        }

        /* ---- partials: weights broadcast from REGISTERS via readlane ----
         * 2 VALU instr per MAC, no memory ops, no waitcnts. */
        float acc[16];
#pragma unroll
        for (int r = 0; r < 16; ++r) {
            float a = 0.0f;
#pragma unroll
            for (int q = 0; q < 4; ++q) {
#pragma unroll
                for (int u = 0; u < 8; ++u) {
                    const float ws = __uint_as_float(
                        __builtin_amdgcn_readlane(__float_as_uint(whreg[u]), r * 4 + q));
                    a = fmaf(ws, hv[q * 8 + u], a);
                }
            }
            acc[r] = a;
        }
        if (layer > 0) {
#pragma unroll
            for (int r = 0; r < 16; ++r) {
                float a = acc[r];
#pragma unroll
                for (int q = 0; q < 4; ++q) {
#pragma unroll
                    for (int u = 0; u < 8; ++u) {
                        const float ws = __uint_as_float(
                            __builtin_amdgcn_readlane(__float_as_uint(wihreg[u]), r * 4 + q));
                        a = fmaf(ws, gv[q * 8 + u], a);
                    }
                }
                acc[r] = a;
            }
        }

        /* ---- cross-wave reduction ---- */
#pragma unroll
        for (int r = 0; r < 16; ++r) red[r][w][b] = acc[r];
        __syncthreads();

        /* completion flag (slot-drain for producer): inputs of step t consumed */
        if (tid == 0) {
            __hip_atomic_store(&flags[(layer * TT + t) * 64 + lb], 1,
                               __ATOMIC_RELAXED, __HIP_MEMORY_SCOPE_AGENT);
        }

        /* ---- cell update: waves 0-3, thread = (cell j = w, b) ---- */
        if (tid < 256) {
            float a0, a1, a2, a3;
            if (layer == 0) { a0 = xv0; a1 = xv1; a2 = xv2; a3 = xv3; }
            else            { a0 = bs0; a1 = bs1; a2 = bs2; a3 = bs3; }
#pragma unroll
            for (int ww = 0; ww < 8; ++ww) {
                a0 += red[w * 4 + 0][ww][b];
                a1 += red[w * 4 + 1][ww][b];
                a2 += red[w * 4 + 2][ww][b];
                a3 += red[w * 4 + 3][ww][b];
            }
            const float ig = sigmoidf_(a0);
            const float fg = sigmoidf_(a1);
            const float gg = tanhf_(a2);
            const float og = sigmoidf_(a3);
            c = fg * c + ig * gg;
            const float h = og * tanhf_(c);
            const unsigned long long pk =
                ((unsigned long long)(unsigned)(t + 1) << 32) |
                (unsigned long long)__float_as_uint(h);
            st_agent_u64(&myU[(size_t)(t & 3) * SLOT_STRIDE
                              + (size_t)(jbase + w) * BB + b], pk);
        }

        __syncthreads();   // red reads done before next step's writes
    }
}

/* ---------------- Kernel 3: FC head on h2[T-1] (tagged-element layout) ---------------- */
__global__ __launch_bounds__(256) void classifier_k(
    const unsigned long long* __restrict__ ringU,
    const float* __restrict__ W1, const float* __restrict__ bfc1,
    const float* __restrict__ W2, const float* __restrict__ bfc2,
    float* __restrict__ out)
{
    __shared__ float z[BB * 128];
    const unsigned long long* h2T = ringU + 2 * LAYER_STRIDE
                                  + (size_t)((TT - 1) & 3) * SLOT_STRIDE;
    const int tid = threadIdx.x;
    for (int idx = tid; idx < BB * 128; idx += 256) {
        const int bb = idx >> 7;
        const int n = idx & 127;
        float acc = bfc1[n];
        const float* wr = W1 + (size_t)n * HD;
        for (int k = 0; k < HD; ++k) {
            const float hval = __uint_as_float((unsigned)h2T[(size_t)k * BB + bb]);
            acc = fmaf(hval, wr[k], acc);
        }
        z[bb * 128 + n] = fmaxf(acc, 0.0f);
    }
    __syncthreads();
    for (int idx = tid; idx < BB * NCLS; idx += 256) {
        const int bb = idx >> 3;
        const int n = idx & 7;
        float acc = bfc2[n];
        const float* zr = &z[bb * 128];
        const float* wr = W2 + (size_t)n * 128;
        for (int k = 0; k < 128; k += 4) {
            const float4 zv = *(const float4*)&zr[k];
            const float4 wv = *(const float4*)&wr[k];
            acc = fmaf(zv.x, wv.x, acc); acc = fmaf(zv.y, wv.y, acc);
            acc = fmaf(zv.z, wv.z, acc); acc = fmaf(zv.w, wv.w, acc);
        }
        out[idx] = acc;
    }
}

extern "C" void kernel_launch(void* const* d_in, const int* in_sizes, int n_in,
                              void* d_out, int out_size, void* d_ws, size_t ws_size,
                              hipStream_t stream) {
    const float* x    = (const float*)d_in[0];
    const float* Wih0 = (const float*)d_in[1];
    const float* Whh0 = (const float*)d_in[2];
    const float* b0   = (const float*)d_in[3];
    const float* Wih1 = (const float*)d_in[4];
    const float* Whh1 = (const float*)d_in[5];
    const float* b1   = (const float*)d_in[6];
    const float* Wih2 = (const float*)d_in[7];
    const float* Whh2 = (const float*)d_in[8];
    const float* b2   = (const float*)d_in[9];
    const float* W1   = (const float*)d_in[10];
    const float* bfc1 = (const float*)d_in[11];
    const float* W2   = (const float*)d_in[12];
    const float* bfc2 = (const float*)d_in[13];

    float* xg0T = (float*)d_ws;                               // B*T*4H fp32 = 134.2 MB
    unsigned long long* ringU =
        (unsigned long long*)(xg0T + (size_t)BB * TT * G4H);  // 3*4*16384 * 8B = 1.57 MB
    int* flags = (int*)(ringU + 3 * LAYER_STRIDE);            // 3*512*64 ints = 393 KB

    xg0_gemm<<<dim3(G4H / GBN, (BB * TT) / GBM), 256, 0, stream>>>(x, Wih0, b0, xg0T);

    const float* xgc = xg0T;
    unsigned long long* ru = ringU;
    int* fl = flags;
    void* args[] = {
        (void*)&xgc, (void*)&Whh0,
        (void*)&Wih1, (void*)&Whh1, (void*)&b1,
        (void*)&Wih2, (void*)&Whh2, (void*)&b2,
        (void*)&ru, (void*)&fl
    };
    hipLaunchCooperativeKernel((void*)lstm_cells, dim3(192), dim3(512), args, 0, stream);

    classifier_k<<<1, 256, 0, stream>>>(ringU, W1, bfc1, W2, bfc2, (float*)d_out);
}